// Round 7
// baseline (102.630 us; speedup 1.0000x reference)
//
#include <hip/hip_runtime.h>
#include <math.h>

namespace {
constexpr int S = 64;
constexpr int NP = 131072;
constexpr int H = 32;
constexpr int BLK = 256;
constexpr int NB = NP / BLK;       // 512
constexpr int CH = 128;            // points per k_main block (2 per lane)
constexpr int NCHUNK = 20;         // 20*128 = 2560 >= max cell count (~2160)

// per-subnet LDS weight slab layout (floats):
//   Win[64] | b_in[32] | W1[1024] | b1[32] | W2[1024] | b2[32] | Wout[32] | b_out[1]
constexpr int LW_WIN  = 0;
constexpr int LW_BIN  = 64;
constexpr int LW_W1   = 96;
constexpr int LW_B1   = 1120;
constexpr int LW_W2   = 1152;
constexpr int LW_B2   = 2176;
constexpr int LW_WOUT = 2208;
constexpr int LW_BOUT = 2240;
constexpr int LW_N    = 2241;
constexpr int LW_STR  = 2244;      // padded stride (16B-aligned rows)

// d_ws layout (ints):
constexpr int WS_HIST = 0;                  // [0,64)
constexpr int WS_OFF  = 64;                 // [64,128)
constexpr int WS_CUR  = 128;                // [128,192)
constexpr int WS_CELL = 192;                // [192, 192+NP)
constexpr int WS_LIST = WS_CELL + NP;       // [+NP)
constexpr int WS_XS   = WS_LIST + NP;       // float2[NP] -> 2*NP ints

__device__ __forceinline__ float dev_exp2(float v) {
    return __builtin_amdgcn_exp2f(v);       // v_exp_f32: 2^v, saturates to inf/0
}
__device__ __forceinline__ float fast_tanh(float v) {
    // tanh(v) = 1 - 2/(e^{2v}+1); exp2 overflow/underflow gives exact +-1 saturation
    float e = dev_exp2(v * 2.8853900817779268f);
    return 1.0f - __fdividef(2.0f, e + 1.0f);
}
__device__ __forceinline__ float fast_sigmoid(float z) {
    return __fdividef(1.0f, 1.0f + dev_exp2(z * -1.4426950408889634f));
}
__device__ __forceinline__ int cell_of(float xx) {
    int c = (int)floorf((xx + 1.0f) * 32.0f);
    return min(S - 1, max(0, c));
}

__global__ void k_zero(int* hist) { hist[threadIdx.x] = 0; }

__global__ __launch_bounds__(BLK) void k_hist(const float* __restrict__ x,
                                              int* __restrict__ hist,
                                              int* __restrict__ cell) {
    __shared__ int lh[S];
    const int tid = threadIdx.x;
    if (tid < S) lh[tid] = 0;
    __syncthreads();
    const int p = blockIdx.x * BLK + tid;
    const int c = cell_of(x[2 * p + 1]);
    cell[p] = c;
    atomicAdd(&lh[c], 1);
    __syncthreads();
    if (tid < S && lh[tid] != 0) atomicAdd(&hist[tid], lh[tid]);
}

__global__ __launch_bounds__(S) void k_off(const int* __restrict__ hist,
                                           int* __restrict__ off,
                                           int* __restrict__ cursor) {
    const int t = threadIdx.x;
    int v = hist[t];
    int sum = v;
    #pragma unroll
    for (int d = 1; d < 64; d <<= 1) {
        int o = __shfl_up(sum, d);
        if (t >= d) sum += o;
    }
    off[t] = sum - v;
    cursor[t] = sum - v;
}

__global__ __launch_bounds__(BLK) void k_scatter(const float* __restrict__ x,
                                                 const int* __restrict__ cell,
                                                 int* __restrict__ cursor,
                                                 int* __restrict__ list,
                                                 float2* __restrict__ xsorted) {
    __shared__ int lh[S];
    __shared__ int lbase[S];
    const int tid = threadIdx.x;
    if (tid < S) lh[tid] = 0;
    __syncthreads();
    const int p = blockIdx.x * BLK + tid;
    const int c = cell[p];
    const int r = atomicAdd(&lh[c], 1);
    __syncthreads();
    if (tid < S && lh[tid] != 0) lbase[tid] = atomicAdd(&cursor[tid], lh[tid]);
    __syncthreads();
    const int pos = lbase[c] + r;
    list[pos] = p;
    xsorted[pos] = ((const float2*)x)[p];
}

// block = 192 threads = 3 waves; wave w evaluates subnet j=c-1+w for 128 points (2/lane).
// Weights for all 3 subnets staged in LDS once per block; inner loop reads them as
// float4 -> ds_read_b128 broadcast (all lanes same addr, conflict-free).
__global__ __launch_bounds__(192, 3) void k_main(
    const float2* __restrict__ xsorted,
    const float* __restrict__ lo_core, const float* __restrict__ hi_core,
    const float* __restrict__ lo_ext,  const float* __restrict__ hi_ext,
    const float* __restrict__ W_in,  const float* __restrict__ b_in,
    const float* __restrict__ W_h1,  const float* __restrict__ b_h1,
    const float* __restrict__ W_h2,  const float* __restrict__ b_h2,
    const float* __restrict__ W_out, const float* __restrict__ b_out,
    const int* __restrict__ hist, const int* __restrict__ off,
    const int* __restrict__ list,
    float* __restrict__ out)
{
    const int c   = blockIdx.x;
    const int cnt = hist[c];
    const int base = blockIdx.y * CH;
    if (base >= cnt) return;

    __shared__ __align__(16) float lw[3][LW_STR];
    __shared__ float lnum[3][CH];
    __shared__ float lden[3][CH];

    const int tid = threadIdx.x;
    // ---- cooperative staging of 3 subnets' weights ----
    for (int i = tid; i < 3 * LW_N; i += 192) {
        const int sl = i / LW_N;
        const int e  = i - sl * LW_N;
        const int j  = c - 1 + sl;
        if (j >= 0 && j < S) {
            float v;
            if      (e < LW_BIN)  v = W_in [j * 64   + e];
            else if (e < LW_W1)   v = b_in [j * 32   + (e - LW_BIN)];
            else if (e < LW_B1)   v = W_h1 [j * 1024 + (e - LW_W1)];
            else if (e < LW_W2)   v = b_h1 [j * 32   + (e - LW_B1)];
            else if (e < LW_B2)   v = W_h2 [j * 1024 + (e - LW_W2)];
            else if (e < LW_WOUT) v = b_h2 [j * 32   + (e - LW_B2)];
            else if (e < LW_BOUT) v = W_out[j * 32   + (e - LW_WOUT)];
            else                  v = b_out[j];
            lw[sl][e] = v;
        }
    }
    __syncthreads();

    const int wid  = tid >> 6;           // 0..2
    const int lane = tid & 63;
    const int o = off[c];
    const int idx0 = base + lane;
    const int idx1 = base + lane + 64;
    const bool act0 = idx0 < cnt;
    const bool act1 = idx1 < cnt;
    const int slot0 = o + (act0 ? idx0 : cnt - 1);
    const int slot1 = o + (act1 ? idx1 : cnt - 1);
    const float2 xv0 = xsorted[slot0];
    const float2 xv1 = xsorted[slot1];
    const float tt0 = xv0.x, xx0 = xv0.y;
    const float tt1 = xv1.x, xx1 = xv1.y;

    float num0 = 0.0f, den0 = 0.0f, num1 = 0.0f, den1 = 0.0f;
    const int j = c - 1 + wid;
    if (j >= 0 && j < S) {                        // wave-uniform
        const int ju = __builtin_amdgcn_readfirstlane(j);
        const float le0 = lo_ext[2*ju+0], he0 = hi_ext[2*ju+0];
        const float le1 = lo_ext[2*ju+1], he1 = hi_ext[2*ju+1];
        const float ic0 = (le0 + he0) * 0.5f, ih0 = __fdividef(1.0f, (he0 - le0) * 0.5f);
        const float ic1 = (le1 + he1) * 0.5f, ih1 = __fdividef(1.0f, (he1 - le1) * 0.5f);
        const float xnA0 = (tt0 - ic0) * ih0, xnA1 = (xx0 - ic1) * ih1;
        const float xnB0 = (tt1 - ic0) * ih0, xnB1 = (xx1 - ic1) * ih1;

        const float* Ws = lw[wid];                // LDS slab for this wave's subnet
        float hA0[H], hB0[H], hA1[H], hB1[H];
        {   // input layer: pairs of neurons per float4
            const float4* Wiv = (const float4*)(Ws + LW_WIN);
            #pragma unroll
            for (int k = 0; k < H; k += 2) {
                const float4 w = Wiv[k >> 1];     // neurons k (x,y), k+1 (z,w)
                const float bk0 = Ws[LW_BIN + k];
                const float bk1 = Ws[LW_BIN + k + 1];
                hA0[k]   = fast_tanh(fmaf(xnA1, w.y, fmaf(xnA0, w.x, bk0)));
                hB0[k]   = fast_tanh(fmaf(xnB1, w.y, fmaf(xnB0, w.x, bk0)));
                hA0[k+1] = fast_tanh(fmaf(xnA1, w.w, fmaf(xnA0, w.z, bk1)));
                hB0[k+1] = fast_tanh(fmaf(xnB1, w.w, fmaf(xnB0, w.z, bk1)));
            }
        }
        {
            const float4* W1v = (const float4*)(Ws + LW_W1);
            #pragma unroll
            for (int k = 0; k < H; ++k) {
                float a0 = Ws[LW_B1 + k], a1 = a0;
                #pragma unroll
                for (int q4 = 0; q4 < H / 4; ++q4) {
                    const float4 w = W1v[k * 8 + q4];
                    a0 = fmaf(hA0[4*q4+0], w.x, a0); a1 = fmaf(hB0[4*q4+0], w.x, a1);
                    a0 = fmaf(hA0[4*q4+1], w.y, a0); a1 = fmaf(hB0[4*q4+1], w.y, a1);
                    a0 = fmaf(hA0[4*q4+2], w.z, a0); a1 = fmaf(hB0[4*q4+2], w.z, a1);
                    a0 = fmaf(hA0[4*q4+3], w.w, a0); a1 = fmaf(hB0[4*q4+3], w.w, a1);
                }
                hA1[k] = fast_tanh(a0);
                hB1[k] = fast_tanh(a1);
            }
        }
        {
            const float4* W2v = (const float4*)(Ws + LW_W2);
            #pragma unroll
            for (int k = 0; k < H; ++k) {
                float a0 = Ws[LW_B2 + k], a1 = a0;
                #pragma unroll
                for (int q4 = 0; q4 < H / 4; ++q4) {
                    const float4 w = W2v[k * 8 + q4];
                    a0 = fmaf(hA1[4*q4+0], w.x, a0); a1 = fmaf(hB1[4*q4+0], w.x, a1);
                    a0 = fmaf(hA1[4*q4+1], w.y, a0); a1 = fmaf(hB1[4*q4+1], w.y, a1);
                    a0 = fmaf(hA1[4*q4+2], w.z, a0); a1 = fmaf(hB1[4*q4+2], w.z, a1);
                    a0 = fmaf(hA1[4*q4+3], w.w, a0); a1 = fmaf(hB1[4*q4+3], w.w, a1);
                }
                hA0[k] = fast_tanh(a0);               // reuse layer-1 arrays
                hB0[k] = fast_tanh(a1);
            }
        }
        float acc0, acc1;
        {
            const float4* Wov = (const float4*)(Ws + LW_WOUT);
            acc0 = Ws[LW_BOUT]; acc1 = acc0;
            #pragma unroll
            for (int q4 = 0; q4 < H / 4; ++q4) {
                const float4 w = Wov[q4];
                acc0 = fmaf(hA0[4*q4+0], w.x, acc0); acc1 = fmaf(hB0[4*q4+0], w.x, acc1);
                acc0 = fmaf(hA0[4*q4+1], w.y, acc0); acc1 = fmaf(hB0[4*q4+1], w.y, acc1);
                acc0 = fmaf(hA0[4*q4+2], w.z, acc0); acc1 = fmaf(hB0[4*q4+2], w.z, acc1);
                acc0 = fmaf(hA0[4*q4+3], w.w, acc0); acc1 = fmaf(hB0[4*q4+3], w.w, acc1);
            }
        }

        float w0 = 1.0f, w1 = 1.0f;
        {
            const float lc = lo_core[2*ju+0], hc = hi_core[2*ju+0];
            const float ov = fmaxf(he0 - hc, lc - le0);
            const float sc = __fdividef(4.0f, fmaf(2.0f * ov, he0 - le0, 1e-8f));
            w0 *= fast_sigmoid(sc * (tt0 - lc)) * fast_sigmoid(sc * (hc - tt0));
            w1 *= fast_sigmoid(sc * (tt1 - lc)) * fast_sigmoid(sc * (hc - tt1));
        }
        {
            const float lc = lo_core[2*ju+1], hc = hi_core[2*ju+1];
            const float ov = fmaxf(he1 - hc, lc - le1);
            const float sc = __fdividef(4.0f, fmaf(2.0f * ov, he1 - le1, 1e-8f));
            w0 *= fast_sigmoid(sc * (xx0 - lc)) * fast_sigmoid(sc * (hc - xx0));
            w1 *= fast_sigmoid(sc * (xx1 - lc)) * fast_sigmoid(sc * (hc - xx1));
        }
        num0 = acc0 * w0; den0 = w0;
        num1 = acc1 * w1; den1 = w1;
    }
    lnum[wid][lane]      = num0;
    lnum[wid][lane + 64] = num1;
    lden[wid][lane]      = den0;
    lden[wid][lane + 64] = den1;
    __syncthreads();

    // wave0 lane l finalizes point l (its pt0); wave1 lane l finalizes point 64+l (its pt1)
    if (wid < 2) {
        const int   pi    = wid * 64 + lane;
        const bool  act   = wid == 0 ? act0  : act1;
        const float ttF   = wid == 0 ? tt0   : tt1;
        const float xxF   = wid == 0 ? xx0   : xx1;
        const int   slotF = wid == 0 ? slot0 : slot1;
        if (act) {
            const float nsum = lnum[0][pi] + lnum[1][pi] + lnum[2][pi];
            const float dsum = lden[0][pi] + lden[1][pi] + lden[2][pi];
            const float u = __fdividef(nsum, dsum + 1e-8f);
            const float g = -sinf(3.14159265358979323846f * xxF);
            const float factor = fast_tanh(xxF + 1.0f) * fast_tanh(xxF - 1.0f) * fast_tanh(ttF);
            out[list[slotF]] = fmaf(factor, u, g);
        }
    }
}
} // namespace

extern "C" void kernel_launch(void* const* d_in, const int* in_sizes, int n_in,
                              void* d_out, int out_size, void* d_ws, size_t ws_size,
                              hipStream_t stream) {
    const float* x       = (const float*)d_in[0];
    const float* lo_core = (const float*)d_in[1];
    const float* hi_core = (const float*)d_in[2];
    const float* lo_ext  = (const float*)d_in[3];
    const float* hi_ext  = (const float*)d_in[4];
    const float* W_in    = (const float*)d_in[5];
    const float* b_in    = (const float*)d_in[6];
    const float* W_h1    = (const float*)d_in[7];
    const float* b_h1    = (const float*)d_in[8];
    const float* W_h2    = (const float*)d_in[9];
    const float* b_h2    = (const float*)d_in[10];
    const float* W_out   = (const float*)d_in[11];
    const float* b_out   = (const float*)d_in[12];
    float* out = (float*)d_out;

    int* ws      = (int*)d_ws;
    int* hist    = ws + WS_HIST;
    int* off     = ws + WS_OFF;
    int* cursor  = ws + WS_CUR;
    int* cell    = ws + WS_CELL;
    int* list    = ws + WS_LIST;
    float2* xsorted = (float2*)(ws + WS_XS);

    hipLaunchKernelGGL(k_zero,    dim3(1),          dim3(S),   0, stream, hist);
    hipLaunchKernelGGL(k_hist,    dim3(NB),         dim3(BLK), 0, stream, x, hist, cell);
    hipLaunchKernelGGL(k_off,     dim3(1),          dim3(S),   0, stream, hist, off, cursor);
    hipLaunchKernelGGL(k_scatter, dim3(NB),         dim3(BLK), 0, stream, x, cell, cursor, list, xsorted);
    hipLaunchKernelGGL(k_main,    dim3(S, NCHUNK),  dim3(192), 0, stream,
        xsorted, lo_core, hi_core, lo_ext, hi_ext, W_in, b_in, W_h1, b_h1,
        W_h2, b_h2, W_out, b_out, hist, off, list, out);
}

// Round 8
// 91.083 us; speedup vs baseline: 1.1268x; 1.1268x over previous
//
#include <hip/hip_runtime.h>
#include <math.h>

namespace {
constexpr int S = 64;
constexpr int NP = 131072;
constexpr int H = 32;
constexpr int BLK = 256;
constexpr int NB = NP / BLK;       // 512
constexpr int WPB = 4;             // independent waves per k_main block
constexpr int CHUNK = 64;          // points per wave
constexpr int NCG = 9;             // chunk-groups: 9*4*64 = 2304 >= max cell count (~2160)

// d_ws layout (ints):
constexpr int WS_OFF  = 0;                    // [0,66)  off[0..64] (65 used, padded even)
constexpr int WS_BH   = 66;                   // blockhist / bases: NB*S
constexpr int WS_CELL = WS_BH + NB * S;       // NP
constexpr int WS_LIST = WS_CELL + NP;         // NP
constexpr int WS_XS   = WS_LIST + NP;         // float2[NP] -> 2*NP ints (even offset)
constexpr int WS_PART = WS_XS + 2 * NP;       // float2[3][NP] -> 6*NP ints (even offset)

__device__ __forceinline__ float dev_exp2(float v) {
    return __builtin_amdgcn_exp2f(v);       // v_exp_f32: 2^v, saturates to inf/0
}
__device__ __forceinline__ float fast_tanh(float v) {
    // tanh(v) = 1 - 2/(e^{2v}+1); exp2 overflow/underflow gives exact +-1 saturation
    float e = dev_exp2(v * 2.8853900817779268f);
    return 1.0f - __fdividef(2.0f, e + 1.0f);
}
__device__ __forceinline__ float fast_sigmoid(float z) {
    return __fdividef(1.0f, 1.0f + dev_exp2(z * -1.4426950408889634f));
}
__device__ __forceinline__ int cell_of(float xx) {
    int c = (int)floorf((xx + 1.0f) * 32.0f);
    return min(S - 1, max(0, c));
}

// per-block histogram, no global atomics
__global__ __launch_bounds__(BLK) void k_hist(const float* __restrict__ x,
                                              int* __restrict__ blockhist,
                                              int* __restrict__ cell) {
    __shared__ int lh[S];
    const int tid = threadIdx.x;
    if (tid < S) lh[tid] = 0;
    __syncthreads();
    const int p = blockIdx.x * BLK + tid;
    const int c = cell_of(x[2 * p + 1]);
    cell[p] = c;
    atomicAdd(&lh[c], 1);                      // LDS atomic only
    __syncthreads();
    if (tid < S) blockhist[blockIdx.x * S + tid] = lh[tid];
}

// one wave: totals, exclusive scan -> off[0..64], blockhist -> per-(block,cell) base
__global__ __launch_bounds__(S) void k_scan(int* __restrict__ blockhist,
                                            int* __restrict__ off) {
    const int t = threadIdx.x;
    int tot = 0;
    for (int b = 0; b < NB; ++b) tot += blockhist[b * S + t];   // coalesced
    int sum = tot;
    #pragma unroll
    for (int d = 1; d < 64; d <<= 1) {
        int o = __shfl_up(sum, d);
        if (t >= d) sum += o;
    }
    const int o = sum - tot;                   // exclusive
    off[t] = o;
    if (t == 63) off[64] = sum;                // == NP
    int run = o;
    for (int b = 0; b < NB; ++b) {
        int v = blockhist[b * S + t];
        blockhist[b * S + t] = run;
        run += v;
    }
}

// scatter: LDS rank + precomputed per-(block,cell) base; also pre-gather x to sorted order
__global__ __launch_bounds__(BLK) void k_scatter(const float* __restrict__ x,
                                                 const int* __restrict__ cell,
                                                 const int* __restrict__ base,
                                                 int* __restrict__ list,
                                                 float2* __restrict__ xsorted) {
    __shared__ int lh[S];
    __shared__ int lbase[S];
    const int tid = threadIdx.x;
    if (tid < S) { lh[tid] = 0; lbase[tid] = base[blockIdx.x * S + tid]; }
    __syncthreads();
    const int p = blockIdx.x * BLK + tid;
    const int c = cell[p];
    const int r = atomicAdd(&lh[c], 1);        // LDS atomic only
    const int pos = lbase[c] + r;
    list[pos] = p;
    xsorted[pos] = ((const float2*)x)[p];
}

// grid (S, NCG, 3); block = 256 = 4 INDEPENDENT waves (no barriers, no LDS).
// wave = one (cell c, subnet j=c-1+blockIdx.z, 64-point chunk). Writes (num,den) partial.
// j/c are block-uniform scalars -> all weight addressing is SGPR -> s_load.
__global__ __launch_bounds__(256, 6) void k_main(
    const float2* __restrict__ xsorted,
    const float* __restrict__ lo_core, const float* __restrict__ hi_core,
    const float* __restrict__ lo_ext,  const float* __restrict__ hi_ext,
    const float* __restrict__ W_in,  const float* __restrict__ b_in,
    const float* __restrict__ W_h1,  const float* __restrict__ b_h1,
    const float* __restrict__ W_h2,  const float* __restrict__ b_h2,
    const float* __restrict__ W_out, const float* __restrict__ b_out,
    const int* __restrict__ off,
    float2* __restrict__ part)
{
    const int c   = blockIdx.x;
    const int sl  = blockIdx.z;
    const int o   = off[c];
    const int cnt = off[c + 1] - o;
    const int wid  = threadIdx.x >> 6;
    const int lane = threadIdx.x & 63;
    const int base = (blockIdx.y * WPB + wid) * CHUNK;
    if (base >= cnt) return;                    // wave-uniform exit
    const int idx = base + lane;
    const bool act = idx < cnt;
    const int slot = o + (act ? idx : cnt - 1);
    const float2 xv = xsorted[slot];
    const float tt = xv.x, xx = xv.y;

    float num = 0.0f, den = 0.0f;
    const int j = c - 1 + sl;                   // block-uniform (SGPR)
    if (j >= 0 && j < S) {
        const float le0 = lo_ext[2*j+0], he0 = hi_ext[2*j+0];
        const float le1 = lo_ext[2*j+1], he1 = hi_ext[2*j+1];
        const float ic0 = (le0 + he0) * 0.5f, ih0 = __fdividef(1.0f, (he0 - le0) * 0.5f);
        const float ic1 = (le1 + he1) * 0.5f, ih1 = __fdividef(1.0f, (he1 - le1) * 0.5f);
        const float xn0 = (tt - ic0) * ih0;
        const float xn1 = (xx - ic1) * ih1;

        const float* Wi = W_in + j * (H * 2);
        const float* bi = b_in + j * H;
        float h0[H], h1[H];
        #pragma unroll
        for (int k = 0; k < H; ++k) {
            h0[k] = fast_tanh(fmaf(xn1, Wi[2*k+1], fmaf(xn0, Wi[2*k], bi[k])));
        }
        const float* W1 = W_h1 + j * (H * H);
        const float* b1 = b_h1 + j * H;
        #pragma unroll
        for (int k = 0; k < H; ++k) {
            float a = b1[k];
            #pragma unroll
            for (int q = 0; q < H; ++q) a = fmaf(h0[q], W1[k*H+q], a);
            h1[k] = fast_tanh(a);
        }
        const float* W2 = W_h2 + j * (H * H);
        const float* b2 = b_h2 + j * H;
        #pragma unroll
        for (int k = 0; k < H; ++k) {
            float a = b2[k];
            #pragma unroll
            for (int q = 0; q < H; ++q) a = fmaf(h1[q], W2[k*H+q], a);
            h0[k] = fast_tanh(a);               // reuse
        }
        const float* Wo = W_out + j * H;
        float acc = b_out[j];
        #pragma unroll
        for (int q = 0; q < H; ++q) acc = fmaf(h0[q], Wo[q], acc);

        float w = 1.0f;
        {
            const float lc = lo_core[2*j+0], hc = hi_core[2*j+0];
            const float ov = fmaxf(he0 - hc, lc - le0);
            const float sc = __fdividef(4.0f, fmaf(2.0f * ov, he0 - le0, 1e-8f));
            w *= fast_sigmoid(sc * (tt - lc)) * fast_sigmoid(sc * (hc - tt));
        }
        {
            const float lc = lo_core[2*j+1], hc = hi_core[2*j+1];
            const float ov = fmaxf(he1 - hc, lc - le1);
            const float sc = __fdividef(4.0f, fmaf(2.0f * ov, he1 - le1, 1e-8f));
            w *= fast_sigmoid(sc * (xx - lc)) * fast_sigmoid(sc * (hc - xx));
        }
        num = acc * w;
        den = w;
    }
    if (act) part[sl * NP + slot] = make_float2(num, den);
}

// combine 3 subnet partials + hard-BC epilogue, scatter to original order
__global__ __launch_bounds__(BLK) void k_combine(
    const float2* __restrict__ part,
    const float2* __restrict__ xsorted,
    const int* __restrict__ list,
    float* __restrict__ out)
{
    const int i = blockIdx.x * BLK + threadIdx.x;
    const float2 p0 = part[i];
    const float2 p1 = part[NP + i];
    const float2 p2 = part[2 * NP + i];
    const float2 xv = xsorted[i];
    const float tt = xv.x, xx = xv.y;
    const float nsum = p0.x + p1.x + p2.x;
    const float dsum = p0.y + p1.y + p2.y;
    const float u = __fdividef(nsum, dsum + 1e-8f);
    const float g = -sinf(3.14159265358979323846f * xx);
    const float factor = fast_tanh(xx + 1.0f) * fast_tanh(xx - 1.0f) * fast_tanh(tt);
    out[list[i]] = fmaf(factor, u, g);
}
} // namespace

extern "C" void kernel_launch(void* const* d_in, const int* in_sizes, int n_in,
                              void* d_out, int out_size, void* d_ws, size_t ws_size,
                              hipStream_t stream) {
    const float* x       = (const float*)d_in[0];
    const float* lo_core = (const float*)d_in[1];
    const float* hi_core = (const float*)d_in[2];
    const float* lo_ext  = (const float*)d_in[3];
    const float* hi_ext  = (const float*)d_in[4];
    const float* W_in    = (const float*)d_in[5];
    const float* b_in    = (const float*)d_in[6];
    const float* W_h1    = (const float*)d_in[7];
    const float* b_h1    = (const float*)d_in[8];
    const float* W_h2    = (const float*)d_in[9];
    const float* b_h2    = (const float*)d_in[10];
    const float* W_out   = (const float*)d_in[11];
    const float* b_out   = (const float*)d_in[12];
    float* out = (float*)d_out;

    int* ws        = (int*)d_ws;
    int* off       = ws + WS_OFF;
    int* blockhist = ws + WS_BH;      // becomes per-(block,cell) base after k_scan
    int* cell      = ws + WS_CELL;
    int* list      = ws + WS_LIST;
    float2* xsorted = (float2*)(ws + WS_XS);
    float2* part    = (float2*)(ws + WS_PART);

    hipLaunchKernelGGL(k_hist,    dim3(NB),           dim3(BLK), 0, stream, x, blockhist, cell);
    hipLaunchKernelGGL(k_scan,    dim3(1),            dim3(S),   0, stream, blockhist, off);
    hipLaunchKernelGGL(k_scatter, dim3(NB),           dim3(BLK), 0, stream, x, cell, blockhist, list, xsorted);
    hipLaunchKernelGGL(k_main,    dim3(S, NCG, 3),    dim3(256), 0, stream,
        xsorted, lo_core, hi_core, lo_ext, hi_ext, W_in, b_in, W_h1, b_h1,
        W_h2, b_h2, W_out, b_out, off, part);
    hipLaunchKernelGGL(k_combine, dim3(NP / BLK),     dim3(BLK), 0, stream, part, xsorted, list, out);
}

// Round 9
// 86.175 us; speedup vs baseline: 1.1909x; 1.0569x over previous
//
#include <hip/hip_runtime.h>
#include <math.h>

namespace {
constexpr int S = 64;
constexpr int NP = 131072;
constexpr int H = 32;
constexpr int BLK = 256;
constexpr int NB = NP / BLK;       // 512
constexpr int NBK = 3 * S;         // 192 buckets: 3*cell + band
constexpr int WPB = 4;             // waves per k_main block
constexpr int CHUNK = 64;          // points per wave
constexpr int NCG = 9;             // 9*256 = 2304 >= max range (~2160)

// d_ws layout (ints):
constexpr int WS_OFF  = 0;                    // off[0..192] (193 used, pad 194)
constexpr int WS_BH   = 194;                  // blockhist/bases: NB*NBK
constexpr int WS_CELL = WS_BH + NB * NBK;     // NP (bucket key per point)
constexpr int WS_LIST = WS_CELL + NP;         // NP
constexpr int WS_XS   = WS_LIST + NP;         // float2[NP]
constexpr int WS_PART = WS_XS + 2 * NP;       // float2[3][NP]

__device__ __forceinline__ float dev_exp2(float v) {
    return __builtin_amdgcn_exp2f(v);
}
__device__ __forceinline__ float fast_tanh(float v) {
    float e = dev_exp2(v * 2.8853900817779268f);     // e^{2v}
    return 1.0f - __fdividef(2.0f, e + 1.0f);
}
__device__ __forceinline__ float fast_sigmoid(float z) {
    return __fdividef(1.0f, 1.0f + dev_exp2(z * -1.4426950408889634f));
}
// bucket key: identical fp ops used in k_hist and k_combine (determinism)
__device__ __forceinline__ void cell_band(float xx, int& c, float& frac) {
    float pos = (xx + 1.0f) * 32.0f;
    c = min(S - 1, max(0, (int)floorf(pos)));
    frac = pos - (float)c;
}

__global__ __launch_bounds__(BLK) void k_hist(const float* __restrict__ x,
                                              int* __restrict__ blockhist,
                                              int* __restrict__ key) {
    __shared__ int lh[NBK];
    const int tid = threadIdx.x;
    if (tid < NBK) lh[tid] = 0;
    __syncthreads();
    const int p = blockIdx.x * BLK + tid;
    int c; float frac;
    cell_band(x[2 * p + 1], c, frac);
    const int band = (frac > 0.33f ? 1 : 0) + (frac > 0.67f ? 1 : 0);
    const int k = 3 * c + band;
    key[p] = k;
    atomicAdd(&lh[k], 1);                      // LDS atomic only
    __syncthreads();
    if (tid < NBK) blockhist[blockIdx.x * NBK + tid] = lh[tid];
}

// 192 threads (3 waves): totals, exclusive scan -> off[0..192], bases in place
__global__ __launch_bounds__(NBK) void k_scan(int* __restrict__ blockhist,
                                              int* __restrict__ off) {
    const int t = threadIdx.x;
    int tot = 0;
    for (int b = 0; b < NB; ++b) tot += blockhist[b * NBK + t];   // coalesced
    int incl = tot;
    #pragma unroll
    for (int d = 1; d < 64; d <<= 1) {
        int o = __shfl_up(incl, d);
        if ((t & 63) >= d) incl += o;
    }
    __shared__ int wsum[3];
    if ((t & 63) == 63) wsum[t >> 6] = incl;
    __syncthreads();
    int pre = 0;
    for (int w = 0; w < (t >> 6); ++w) pre += wsum[w];
    const int o = pre + incl - tot;            // exclusive
    off[t] = o;
    if (t == NBK - 1) off[NBK] = pre + incl;   // == NP
    int run = o;
    for (int b = 0; b < NB; ++b) {
        int v = blockhist[b * NBK + t];
        blockhist[b * NBK + t] = run;
        run += v;
    }
}

__global__ __launch_bounds__(BLK) void k_scatter(const float* __restrict__ x,
                                                 const int* __restrict__ key,
                                                 const int* __restrict__ base,
                                                 int* __restrict__ list,
                                                 float2* __restrict__ xsorted) {
    __shared__ int lh[NBK];
    __shared__ int lbase[NBK];
    const int tid = threadIdx.x;
    if (tid < NBK) { lh[tid] = 0; lbase[tid] = base[blockIdx.x * NBK + tid]; }
    __syncthreads();
    const int p = blockIdx.x * BLK + tid;
    const int k = key[p];
    const int r = atomicAdd(&lh[k], 1);        // LDS atomic only
    const int pos = lbase[k] + r;
    list[pos] = p;
    xsorted[pos] = ((const float2*)x)[p];
}

// grid (S, NCG, 3); block = 256 = 4 independent waves (no barriers/LDS).
// z=0: subnet j over its own cell (all bands)     slots [off[3j],   off[3j+3])
// z=1: subnet j as LEFT neighbor of cell j+1 (A,B) slots [off[3j+3], off[3j+5])
// z=2: subnet j as RIGHT neighbor of cell j-1 (B,C) slots [off[3j-2], off[3j])
__global__ __launch_bounds__(256, 4) void k_main(
    const float2* __restrict__ xsorted,
    const float* __restrict__ lo_core, const float* __restrict__ hi_core,
    const float* __restrict__ lo_ext,  const float* __restrict__ hi_ext,
    const float* __restrict__ W_in,  const float* __restrict__ b_in,
    const float* __restrict__ W_h1,  const float* __restrict__ b_h1,
    const float* __restrict__ W_h2,  const float* __restrict__ b_h2,
    const float* __restrict__ W_out, const float* __restrict__ b_out,
    const int* __restrict__ off,
    float2* __restrict__ part)
{
    const int j = blockIdx.x;
    const int z = blockIdx.z;
    int lo, hi;
    if (z == 0)      { lo = off[3*j];     hi = off[3*j+3]; }
    else if (z == 1) { if (j + 1 >= S) return; lo = off[3*j+3]; hi = off[3*j+5]; }
    else             { if (j == 0)     return; lo = off[3*j-2]; hi = off[3*j]; }
    const int cnt = hi - lo;
    const int wid  = threadIdx.x >> 6;
    const int lane = threadIdx.x & 63;
    const int base = (blockIdx.y * WPB + wid) * CHUNK;
    if (base >= cnt) return;                    // wave-uniform exit
    const int idx = base + lane;
    const bool act = idx < cnt;
    const int slot = lo + (act ? idx : cnt - 1);
    const float2 xv = xsorted[slot];
    const float tt = xv.x, xx = xv.y;

    const float le0 = lo_ext[2*j+0], he0 = hi_ext[2*j+0];
    const float le1 = lo_ext[2*j+1], he1 = hi_ext[2*j+1];
    const float ic0 = (le0 + he0) * 0.5f, ih0 = __fdividef(1.0f, (he0 - le0) * 0.5f);
    const float ic1 = (le1 + he1) * 0.5f, ih1 = __fdividef(1.0f, (he1 - le1) * 0.5f);
    const float xn0 = (tt - ic0) * ih0;
    const float xn1 = (xx - ic1) * ih1;

    const float* Wi = W_in + j * (H * 2);
    const float* bi = b_in + j * H;
    float h0[H], h1[H];
    #pragma unroll
    for (int k = 0; k < H; ++k) {
        h0[k] = fast_tanh(fmaf(xn1, Wi[2*k+1], fmaf(xn0, Wi[2*k], bi[k])));
    }
    const float* W1 = W_h1 + j * (H * H);
    const float* b1 = b_h1 + j * H;
    #pragma unroll
    for (int k = 0; k < H; ++k) {
        float a = b1[k];
        #pragma unroll
        for (int q = 0; q < H; ++q) a = fmaf(h0[q], W1[k*H+q], a);
        h1[k] = fast_tanh(a);
    }
    const float* W2 = W_h2 + j * (H * H);
    const float* b2 = b_h2 + j * H;
    #pragma unroll
    for (int k = 0; k < H; ++k) {
        float a = b2[k];
        #pragma unroll
        for (int q = 0; q < H; ++q) a = fmaf(h1[q], W2[k*H+q], a);
        h0[k] = fast_tanh(a);                   // reuse
    }
    const float* Wo = W_out + j * H;
    float acc = b_out[j];
    #pragma unroll
    for (int q = 0; q < H; ++q) acc = fmaf(h0[q], Wo[q], acc);

    float w = 1.0f;
    {
        const float lc = lo_core[2*j+0], hc = hi_core[2*j+0];
        const float ov = fmaxf(he0 - hc, lc - le0);
        const float sc = __fdividef(4.0f, fmaf(2.0f * ov, he0 - le0, 1e-8f));
        w *= fast_sigmoid(sc * (tt - lc)) * fast_sigmoid(sc * (hc - tt));
    }
    {
        const float lc = lo_core[2*j+1], hc = hi_core[2*j+1];
        const float ov = fmaxf(he1 - hc, lc - le1);
        const float sc = __fdividef(4.0f, fmaf(2.0f * ov, he1 - le1, 1e-8f));
        w *= fast_sigmoid(sc * (xx - lc)) * fast_sigmoid(sc * (hc - xx));
    }
    if (act) part[z * NP + slot] = make_float2(acc * w, w);
}

// combine (left, own, right in reference j-order) + hard-BC epilogue
__global__ __launch_bounds__(BLK) void k_combine(
    const float2* __restrict__ part,
    const float2* __restrict__ xsorted,
    const int* __restrict__ list,
    float* __restrict__ out)
{
    const int i = blockIdx.x * BLK + threadIdx.x;
    const float2 xv = xsorted[i];
    const float tt = xv.x, xx = xv.y;
    int c; float frac;
    cell_band(xx, c, frac);
    float nsum = 0.0f, dsum = 0.0f;
    if (c > 0 && !(frac > 0.67f)) {            // left subnet written by z=1 of j=c-1
        const float2 p1 = part[NP + i];
        nsum = p1.x; dsum = p1.y;
    }
    const float2 p0 = part[i];                 // own subnet (z=0)
    nsum += p0.x; dsum += p0.y;
    if (c < S - 1 && frac > 0.33f) {           // right subnet written by z=2 of j=c+1
        const float2 p2 = part[2 * NP + i];
        nsum += p2.x; dsum += p2.y;
    }
    const float u = __fdividef(nsum, dsum + 1e-8f);
    const float g = -sinf(3.14159265358979323846f * xx);
    const float factor = fast_tanh(xx + 1.0f) * fast_tanh(xx - 1.0f) * fast_tanh(tt);
    out[list[i]] = fmaf(factor, u, g);
}
} // namespace

extern "C" void kernel_launch(void* const* d_in, const int* in_sizes, int n_in,
                              void* d_out, int out_size, void* d_ws, size_t ws_size,
                              hipStream_t stream) {
    const float* x       = (const float*)d_in[0];
    const float* lo_core = (const float*)d_in[1];
    const float* hi_core = (const float*)d_in[2];
    const float* lo_ext  = (const float*)d_in[3];
    const float* hi_ext  = (const float*)d_in[4];
    const float* W_in    = (const float*)d_in[5];
    const float* b_in    = (const float*)d_in[6];
    const float* W_h1    = (const float*)d_in[7];
    const float* b_h1    = (const float*)d_in[8];
    const float* W_h2    = (const float*)d_in[9];
    const float* b_h2    = (const float*)d_in[10];
    const float* W_out   = (const float*)d_in[11];
    const float* b_out   = (const float*)d_in[12];
    float* out = (float*)d_out;

    int* ws        = (int*)d_ws;
    int* off       = ws + WS_OFF;
    int* blockhist = ws + WS_BH;      // becomes per-(block,bucket) base after k_scan
    int* key       = ws + WS_CELL;
    int* list      = ws + WS_LIST;
    float2* xsorted = (float2*)(ws + WS_XS);
    float2* part    = (float2*)(ws + WS_PART);

    hipLaunchKernelGGL(k_hist,    dim3(NB),        dim3(BLK), 0, stream, x, blockhist, key);
    hipLaunchKernelGGL(k_scan,    dim3(1),         dim3(NBK), 0, stream, blockhist, off);
    hipLaunchKernelGGL(k_scatter, dim3(NB),        dim3(BLK), 0, stream, x, key, blockhist, list, xsorted);
    hipLaunchKernelGGL(k_main,    dim3(S, NCG, 3), dim3(256), 0, stream,
        xsorted, lo_core, hi_core, lo_ext, hi_ext, W_in, b_in, W_h1, b_h1,
        W_h2, b_h2, W_out, b_out, off, part);
    hipLaunchKernelGGL(k_combine, dim3(NP / BLK),  dim3(BLK), 0, stream, part, xsorted, list, out);
}

// Round 10
// 77.915 us; speedup vs baseline: 1.3172x; 1.1060x over previous
//
#include <hip/hip_runtime.h>
#include <math.h>

namespace {
constexpr int S = 64;
constexpr int NP = 131072;
constexpr int H = 32;
constexpr int BLK = 256;
constexpr int NB = NP / BLK;       // 512
constexpr int NBK = 3 * S;         // 192 buckets: 3*cell + band
constexpr int WPB = 4;             // waves per k_main block
constexpr int CHUNK = 64;          // points per wave
constexpr int NCG = 9;             // 9*256 = 2304 >= max range (~2160)

typedef float v2f __attribute__((ext_vector_type(2)));

// d_ws layout (ints):
constexpr int WS_OFF  = 0;                    // off[0..192] (193 used, pad 194)
constexpr int WS_BH   = 194;                  // blockhist/bases: NB*NBK
constexpr int WS_CELL = WS_BH + NB * NBK;     // NP (bucket key per point)
constexpr int WS_LIST = WS_CELL + NP;         // NP
constexpr int WS_XS   = WS_LIST + NP;         // float2[NP]
constexpr int WS_PART = WS_XS + 2 * NP;       // float2[3][NP]

__device__ __forceinline__ float dev_exp2(float v) {
    return __builtin_amdgcn_exp2f(v);
}
__device__ __forceinline__ float fast_tanh(float v) {
    float e = dev_exp2(v * 2.8853900817779268f);     // e^{2v}
    return 1.0f - __fdividef(2.0f, e + 1.0f);
}
__device__ __forceinline__ float fast_sigmoid(float z) {
    return __fdividef(1.0f, 1.0f + dev_exp2(z * -1.4426950408889634f));
}
// bucket key: identical fp ops used in k_hist and k_combine (determinism)
__device__ __forceinline__ void cell_band(float xx, int& c, float& frac) {
    float pos = (xx + 1.0f) * 32.0f;
    c = min(S - 1, max(0, (int)floorf(pos)));
    frac = pos - (float)c;
}

__global__ __launch_bounds__(BLK) void k_hist(const float* __restrict__ x,
                                              int* __restrict__ blockhist,
                                              int* __restrict__ key) {
    __shared__ int lh[NBK];
    const int tid = threadIdx.x;
    if (tid < NBK) lh[tid] = 0;
    __syncthreads();
    const int p = blockIdx.x * BLK + tid;
    int c; float frac;
    cell_band(x[2 * p + 1], c, frac);
    const int band = (frac > 0.33f ? 1 : 0) + (frac > 0.67f ? 1 : 0);
    const int k = 3 * c + band;
    key[p] = k;
    atomicAdd(&lh[k], 1);                      // LDS atomic only
    __syncthreads();
    if (tid < NBK) blockhist[blockIdx.x * NBK + tid] = lh[tid];
}

// 192 threads (3 waves): totals, exclusive scan -> off[0..192], bases in place
__global__ __launch_bounds__(NBK) void k_scan(int* __restrict__ blockhist,
                                              int* __restrict__ off) {
    const int t = threadIdx.x;
    int tot = 0;
    for (int b = 0; b < NB; ++b) tot += blockhist[b * NBK + t];   // coalesced
    int incl = tot;
    #pragma unroll
    for (int d = 1; d < 64; d <<= 1) {
        int o = __shfl_up(incl, d);
        if ((t & 63) >= d) incl += o;
    }
    __shared__ int wsum[3];
    if ((t & 63) == 63) wsum[t >> 6] = incl;
    __syncthreads();
    int pre = 0;
    for (int w = 0; w < (t >> 6); ++w) pre += wsum[w];
    const int o = pre + incl - tot;            // exclusive
    off[t] = o;
    if (t == NBK - 1) off[NBK] = pre + incl;   // == NP
    int run = o;
    for (int b = 0; b < NB; ++b) {
        int v = blockhist[b * NBK + t];
        blockhist[b * NBK + t] = run;
        run += v;
    }
}

__global__ __launch_bounds__(BLK) void k_scatter(const float* __restrict__ x,
                                                 const int* __restrict__ key,
                                                 const int* __restrict__ base,
                                                 int* __restrict__ list,
                                                 float2* __restrict__ xsorted) {
    __shared__ int lh[NBK];
    __shared__ int lbase[NBK];
    const int tid = threadIdx.x;
    if (tid < NBK) { lh[tid] = 0; lbase[tid] = base[blockIdx.x * NBK + tid]; }
    __syncthreads();
    const int p = blockIdx.x * BLK + tid;
    const int k = key[p];
    const int r = atomicAdd(&lh[k], 1);        // LDS atomic only
    const int pos = lbase[k] + r;
    list[pos] = p;
    xsorted[pos] = ((const float2*)x)[p];
}

// grid (S, NCG, 3); block = 256 = 4 independent waves (no barriers/LDS).
// z=0: subnet j over its own cell (all bands)      slots [off[3j],   off[3j+3])
// z=1: subnet j as LEFT neighbor of cell j+1 (A,B)  slots [off[3j+3], off[3j+5])
// z=2: subnet j as RIGHT neighbor of cell j-1 (B,C) slots [off[3j-2], off[3j])
// All dot-products in packed-f32 (v_pk_fma_f32): half the insts, half the code.
__global__ __launch_bounds__(256, 3) void k_main(
    const float2* __restrict__ xsorted,
    const float* __restrict__ lo_core, const float* __restrict__ hi_core,
    const float* __restrict__ lo_ext,  const float* __restrict__ hi_ext,
    const float* __restrict__ W_in,  const float* __restrict__ b_in,
    const float* __restrict__ W_h1,  const float* __restrict__ b_h1,
    const float* __restrict__ W_h2,  const float* __restrict__ b_h2,
    const float* __restrict__ W_out, const float* __restrict__ b_out,
    const int* __restrict__ off,
    float2* __restrict__ part)
{
    const int j = blockIdx.x;
    const int z = blockIdx.z;
    int lo, hi;
    if (z == 0)      { lo = off[3*j];     hi = off[3*j+3]; }
    else if (z == 1) { if (j + 1 >= S) return; lo = off[3*j+3]; hi = off[3*j+5]; }
    else             { if (j == 0)     return; lo = off[3*j-2]; hi = off[3*j]; }
    const int cnt = hi - lo;
    const int wid  = threadIdx.x >> 6;
    const int lane = threadIdx.x & 63;
    const int base = (blockIdx.y * WPB + wid) * CHUNK;
    if (base >= cnt) return;                    // wave-uniform exit
    const int idx = base + lane;
    const bool act = idx < cnt;
    const int slot = lo + (act ? idx : cnt - 1);
    const float2 xv = xsorted[slot];
    const float tt = xv.x, xx = xv.y;

    const float le0 = lo_ext[2*j+0], he0 = hi_ext[2*j+0];
    const float le1 = lo_ext[2*j+1], he1 = hi_ext[2*j+1];
    const float ic0 = (le0 + he0) * 0.5f, ih0 = __fdividef(1.0f, (he0 - le0) * 0.5f);
    const float ic1 = (le1 + he1) * 0.5f, ih1 = __fdividef(1.0f, (he1 - le1) * 0.5f);
    const float xn0 = (tt - ic0) * ih0;
    const float xn1 = (xx - ic1) * ih1;
    const v2f xn = {xn0, xn1};

    v2f h0[H/2], h1[H/2];                       // activations as packed pairs

    {   // input layer: neuron k weight pair = {W[2k],W[2k+1]}
        const v2f* Wiv = (const v2f*)(W_in + j * (H * 2));
        const float* bi = b_in + j * H;
        #pragma unroll
        for (int k2 = 0; k2 < H/2; ++k2) {
            v2f aA = __builtin_elementwise_fma(xn, Wiv[2*k2+0], (v2f){bi[2*k2+0], 0.0f});
            v2f aB = __builtin_elementwise_fma(xn, Wiv[2*k2+1], (v2f){bi[2*k2+1], 0.0f});
            h0[k2] = (v2f){fast_tanh(aA.x + aA.y), fast_tanh(aB.x + aB.y)};
        }
    }
    {   // hidden layer 1: neurons in pairs, two independent packed chains
        const v2f* W1v = (const v2f*)(W_h1 + j * (H * H));
        const float* b1 = b_h1 + j * H;
        #pragma unroll
        for (int k2 = 0; k2 < H/2; ++k2) {
            const v2f* rowA = W1v + (2*k2) * (H/2);
            const v2f* rowB = rowA + (H/2);
            v2f aA = {b1[2*k2+0], 0.0f};
            v2f aB = {b1[2*k2+1], 0.0f};
            #pragma unroll
            for (int q2 = 0; q2 < H/2; ++q2) {
                aA = __builtin_elementwise_fma(h0[q2], rowA[q2], aA);
                aB = __builtin_elementwise_fma(h0[q2], rowB[q2], aB);
            }
            h1[k2] = (v2f){fast_tanh(aA.x + aA.y), fast_tanh(aB.x + aB.y)};
        }
    }
    {   // hidden layer 2
        const v2f* W2v = (const v2f*)(W_h2 + j * (H * H));
        const float* b2 = b_h2 + j * H;
        #pragma unroll
        for (int k2 = 0; k2 < H/2; ++k2) {
            const v2f* rowA = W2v + (2*k2) * (H/2);
            const v2f* rowB = rowA + (H/2);
            v2f aA = {b2[2*k2+0], 0.0f};
            v2f aB = {b2[2*k2+1], 0.0f};
            #pragma unroll
            for (int q2 = 0; q2 < H/2; ++q2) {
                aA = __builtin_elementwise_fma(h1[q2], rowA[q2], aA);
                aB = __builtin_elementwise_fma(h1[q2], rowB[q2], aB);
            }
            h0[k2] = (v2f){fast_tanh(aA.x + aA.y), fast_tanh(aB.x + aB.y)};   // reuse
        }
    }
    float acc;
    {   // output layer
        const v2f* Wov = (const v2f*)(W_out + j * H);
        v2f a = {b_out[j], 0.0f};
        #pragma unroll
        for (int q2 = 0; q2 < H/2; ++q2) {
            a = __builtin_elementwise_fma(h0[q2], Wov[q2], a);
        }
        acc = a.x + a.y;
    }

    float w = 1.0f;
    {
        const float lc = lo_core[2*j+0], hc = hi_core[2*j+0];
        const float ov = fmaxf(he0 - hc, lc - le0);
        const float sc = __fdividef(4.0f, fmaf(2.0f * ov, he0 - le0, 1e-8f));
        w *= fast_sigmoid(sc * (tt - lc)) * fast_sigmoid(sc * (hc - tt));
    }
    {
        const float lc = lo_core[2*j+1], hc = hi_core[2*j+1];
        const float ov = fmaxf(he1 - hc, lc - le1);
        const float sc = __fdividef(4.0f, fmaf(2.0f * ov, he1 - le1, 1e-8f));
        w *= fast_sigmoid(sc * (xx - lc)) * fast_sigmoid(sc * (hc - xx));
    }
    if (act) part[z * NP + slot] = make_float2(acc * w, w);
}

// combine (left, own, right in reference j-order) + hard-BC epilogue
__global__ __launch_bounds__(BLK) void k_combine(
    const float2* __restrict__ part,
    const float2* __restrict__ xsorted,
    const int* __restrict__ list,
    float* __restrict__ out)
{
    const int i = blockIdx.x * BLK + threadIdx.x;
    const float2 xv = xsorted[i];
    const float tt = xv.x, xx = xv.y;
    int c; float frac;
    cell_band(xx, c, frac);
    float nsum = 0.0f, dsum = 0.0f;
    if (c > 0 && !(frac > 0.67f)) {            // left subnet written by z=1 of j=c-1
        const float2 p1 = part[NP + i];
        nsum = p1.x; dsum = p1.y;
    }
    const float2 p0 = part[i];                 // own subnet (z=0)
    nsum += p0.x; dsum += p0.y;
    if (c < S - 1 && frac > 0.33f) {           // right subnet written by z=2 of j=c+1
        const float2 p2 = part[2 * NP + i];
        nsum += p2.x; dsum += p2.y;
    }
    const float u = __fdividef(nsum, dsum + 1e-8f);
    const float g = -sinf(3.14159265358979323846f * xx);
    const float factor = fast_tanh(xx + 1.0f) * fast_tanh(xx - 1.0f) * fast_tanh(tt);
    out[list[i]] = fmaf(factor, u, g);
}
} // namespace

extern "C" void kernel_launch(void* const* d_in, const int* in_sizes, int n_in,
                              void* d_out, int out_size, void* d_ws, size_t ws_size,
                              hipStream_t stream) {
    const float* x       = (const float*)d_in[0];
    const float* lo_core = (const float*)d_in[1];
    const float* hi_core = (const float*)d_in[2];
    const float* lo_ext  = (const float*)d_in[3];
    const float* hi_ext  = (const float*)d_in[4];
    const float* W_in    = (const float*)d_in[5];
    const float* b_in    = (const float*)d_in[6];
    const float* W_h1    = (const float*)d_in[7];
    const float* b_h1    = (const float*)d_in[8];
    const float* W_h2    = (const float*)d_in[9];
    const float* b_h2    = (const float*)d_in[10];
    const float* W_out   = (const float*)d_in[11];
    const float* b_out   = (const float*)d_in[12];
    float* out = (float*)d_out;

    int* ws        = (int*)d_ws;
    int* off       = ws + WS_OFF;
    int* blockhist = ws + WS_BH;      // becomes per-(block,bucket) base after k_scan
    int* key       = ws + WS_CELL;
    int* list      = ws + WS_LIST;
    float2* xsorted = (float2*)(ws + WS_XS);
    float2* part    = (float2*)(ws + WS_PART);

    hipLaunchKernelGGL(k_hist,    dim3(NB),        dim3(BLK), 0, stream, x, blockhist, key);
    hipLaunchKernelGGL(k_scan,    dim3(1),         dim3(NBK), 0, stream, blockhist, off);
    hipLaunchKernelGGL(k_scatter, dim3(NB),        dim3(BLK), 0, stream, x, key, blockhist, list, xsorted);
    hipLaunchKernelGGL(k_main,    dim3(S, NCG, 3), dim3(256), 0, stream,
        xsorted, lo_core, hi_core, lo_ext, hi_ext, W_in, b_in, W_h1, b_h1,
        W_h2, b_h2, W_out, b_out, off, part);
    hipLaunchKernelGGL(k_combine, dim3(NP / BLK),  dim3(BLK), 0, stream, part, xsorted, list, out);
}